// Round 11
// baseline (768.437 us; speedup 1.0000x reference)
//
#include <hip/hip_runtime.h>
#include <hip/hip_bf16.h>

typedef _Float16 f16;
typedef _Float16 f16x4 __attribute__((ext_vector_type(4)));
typedef _Float16 f16x8 __attribute__((ext_vector_type(8)));
typedef float f32x4 __attribute__((ext_vector_type(4)));

__device__ __forceinline__ void gload16(const void* g, void* l) {
    __builtin_amdgcn_global_load_lds(
        (const __attribute__((address_space(1))) void*)g,
        (__attribute__((address_space(3))) void*)l, 16, 0, 0);
}

#define FENCE asm volatile("" ::: "memory")
#define BARRIER do { FENCE; __builtin_amdgcn_s_barrier(); FENCE; } while (0)

// ===========================================================================
// 8-phase 256x256 BT-GEMM core (verified r8): per K-tile 4 phases, one
// C-quadrant each; stage next tile A at ph1, B at ph2; single vmcnt(0) at ph4.
// ===========================================================================
#define PHASE_MFMA(QI, QJ)                                                    \
    __builtin_amdgcn_s_setprio(1);                                            \
    _Pragma("unroll")                                                         \
    for (int ks = 0; ks < 2; ++ks)                                            \
      _Pragma("unroll")                                                       \
      for (int i = 0; i < 4; ++i)                                             \
        _Pragma("unroll")                                                     \
        for (int j = 0; j < 2; ++j)                                           \
          acc[(QI)*4 + i][(QJ)*2 + j] = __builtin_amdgcn_mfma_f32_16x16x32_f16( \
              a[i][ks], b[j][ks], acc[(QI)*4 + i][(QJ)*2 + j], 0, 0, 0);      \
    __builtin_amdgcn_s_setprio(0);

#define BT8_BODY(KBASE, NTILES)                                               \
    const int rr8 = lane >> 3;                                                \
    const int cs  = ((lane & 7) ^ rr8) << 3;                                  \
    const int ldsr = wid << 3;                                                \
    auto stageA = [&](int kt, int c, int h) {                                 \
        const size_t g0 = (size_t)(bm + (h << 7) + ldsr + rr8) * lda + (KBASE) + kt + cs; \
        gload16(A + g0,                      &sA[c][((h << 7) + ldsr) << 6]); \
        gload16(A + g0 + ((size_t)lda << 6), &sA[c][((h << 7) + 64 + ldsr) << 6]); \
    };                                                                        \
    auto stageB = [&](int kt, int c, int h) {                                 \
        const size_t g0 = (size_t)(bn + (h << 7) + ldsr + rr8) * ldb + (KBASE) + kt + cs; \
        gload16(B + g0,                      &sB[c][((h << 7) + ldsr) << 6]); \
        gload16(B + g0 + ((size_t)ldb << 6), &sB[c][((h << 7) + 64 + ldsr) << 6]); \
    };                                                                        \
    f32x4 acc[8][4] = {};                                                     \
    f16x8 a[4][2], b[2][2];                                                   \
    auto loadA = [&](int c, int qi) {                                         \
        _Pragma("unroll")                                                     \
        for (int i = 0; i < 4; ++i) {                                         \
            const int ra = wr * 128 + (qi * 4 + i) * 16 + (lane & 15);        \
            const int swz = (ra & 7) << 3;                                    \
            _Pragma("unroll")                                                 \
            for (int ks = 0; ks < 2; ++ks) {                                  \
                const int kk = ks * 32 + (lane >> 4) * 8;                     \
                a[i][ks] = *(const f16x8*)(&sA[c][(ra << 6) + (kk ^ swz)]);   \
            }                                                                 \
        }                                                                     \
    };                                                                        \
    auto loadB = [&](int c, int qj) {                                         \
        _Pragma("unroll")                                                     \
        for (int j = 0; j < 2; ++j) {                                         \
            const int rb = wc * 64 + (qj * 2 + j) * 16 + (lane & 15);         \
            const int swz = (rb & 7) << 3;                                    \
            _Pragma("unroll")                                                 \
            for (int ks = 0; ks < 2; ++ks) {                                  \
                const int kk = ks * 32 + (lane >> 4) * 8;                     \
                b[j][ks] = *(const f16x8*)(&sB[c][(rb << 6) + (kk ^ swz)]);   \
            }                                                                 \
        }                                                                     \
    };                                                                        \
    stageA(0, 0, 0); stageA(0, 0, 1); stageB(0, 0, 0); stageB(0, 0, 1);       \
    asm volatile("s_waitcnt vmcnt(0)" ::: "memory");                          \
    BARRIER;                                                                  \
    for (int g = 0; g < (NTILES); ++g) {                                      \
        const int c = g & 1, cn = c ^ 1;                                      \
        const int kn = (g + 1) << 6;                                          \
        const bool more = (g + 1) < (NTILES);                                 \
        loadA(c, 0); loadB(c, 0);                                             \
        if (more) { stageA(kn, cn, 0); stageA(kn, cn, 1); }                   \
        BARRIER; PHASE_MFMA(0, 0); BARRIER;                                   \
        loadB(c, 1);                                                          \
        if (more) { stageB(kn, cn, 0); stageB(kn, cn, 1); }                   \
        BARRIER; PHASE_MFMA(0, 1); BARRIER;                                   \
        loadA(c, 1); loadB(c, 0);                                             \
        BARRIER; PHASE_MFMA(1, 0); BARRIER;                                   \
        loadB(c, 1);                                                          \
        asm volatile("s_waitcnt vmcnt(0)" ::: "memory");                      \
        BARRIER; PHASE_MFMA(1, 1); BARRIER;                                   \
    }

template<bool F16OUT>
__global__ __launch_bounds__(512) void gemm_bt8(
    const f16* __restrict__ A, const f16* __restrict__ B, void* __restrict__ Cv,
    int K, int lda, int ldb, int ldc, float scale, int nbn)
{
    __shared__ f16 sA[2][256 * 64];
    __shared__ f16 sB[2][256 * 64];
    const int tid = threadIdx.x, lane = tid & 63, wid = tid >> 6;
    const int wr = wid >> 2, wc = wid & 3;
    const int cpx = gridDim.x >> 3;
    const int wg = (blockIdx.x & 7) * cpx + (blockIdx.x >> 3);
    const int bm = (wg / nbn) << 8, bn = (wg % nbn) << 8;

    BT8_BODY(0, K >> 6)

#pragma unroll
    for (int i = 0; i < 8; ++i)
#pragma unroll
        for (int j = 0; j < 4; ++j)
#pragma unroll
            for (int r = 0; r < 4; ++r) {
                const int row = bm + wr * 128 + i * 16 + ((lane >> 4) << 2) + r;
                const int col = bn + wc * 64 + j * 16 + (lane & 15);
                if constexpr (F16OUT)
                    ((f16*)Cv)[(size_t)row * ldc + col] = (f16)(acc[i][j][r] * scale);
                else
                    ((float*)Cv)[(size_t)row * ldc + col] = acc[i][j][r] * scale;
            }
}

// ===========================================================================
// PV: bt8 core + split-K=4 (blockIdx.y = K-chunk of 1024) + atomic epilogue.
// Grid (64, 4) = 256 blocks = 1/CU — the proven bt8 regime.
// ===========================================================================
__global__ __launch_bounds__(512) void gemm_pv8(
    const f16* __restrict__ A, const f16* __restrict__ B, float* __restrict__ C,
    int lda, int ldb, int ldc, float scale)
{
    __shared__ f16 sA[2][256 * 64];
    __shared__ f16 sB[2][256 * 64];
    const int tid = threadIdx.x, lane = tid & 63, wid = tid >> 6;
    const int wr = wid >> 2, wc = wid & 3;
    const int cpx = gridDim.x >> 3;
    const int wg = (blockIdx.x & 7) * cpx + (blockIdx.x >> 3);
    const int bm = (wg >> 2) << 8, bn = (wg & 3) << 8;
    const int kbase = blockIdx.y << 10;

    BT8_BODY(kbase, 16)

    // 4 commutative atomic adds per element onto zeroed C
#pragma unroll
    for (int i = 0; i < 8; ++i)
#pragma unroll
        for (int j = 0; j < 4; ++j)
#pragma unroll
            for (int r = 0; r < 4; ++r) {
                const int row = bm + wr * 128 + i * 16 + ((lane >> 4) << 2) + r;
                const int col = bn + wc * 64 + j * 16 + (lane & 15);
                atomicAdd(&C[(size_t)row * ldc + col], acc[i][j][r] * scale);
            }
}

// ===========================================================================
// 128x128 BT-GEMM, F16IN + PIPE (verified) — used for vT.
// ===========================================================================
template<bool F16IN, bool F16OUT, bool PIPE>
__global__ __launch_bounds__(256) void gemm_bt(
    const void* __restrict__ Av, const void* __restrict__ Bv, void* __restrict__ Cv,
    int K, int lda, int ldb, int ldc, float scale)
{
    constexpr int NB = PIPE ? 2 : 1;
    __shared__ f16 sA[NB][128 * 64];
    __shared__ f16 sB[NB][128 * 64];
    const int tid = threadIdx.x, lane = tid & 63, wid = tid >> 6;
    const int wr = wid >> 1, wc = wid & 1;
    const int bm = blockIdx.x * 128, bn = blockIdx.y * 128;

    f32x4 acc[4][4] = {};

    auto stage16 = [&](int kt, int bsel) {
        const f16* A = (const f16*)Av;
        const f16* B = (const f16*)Bv;
        const int rsub = lane >> 3;
        const int csw = ((lane & 7) ^ rsub) << 3;
#pragma unroll
        for (int i = 0; i < 4; ++i) {
            const int rb = (wid * 4 + i) * 8;
            gload16(A + (size_t)(bm + rb + rsub) * lda + kt + csw, &sA[bsel][rb * 64]);
            gload16(B + (size_t)(bn + rb + rsub) * ldb + kt + csw, &sB[bsel][rb * 64]);
        }
    };

    auto compute = [&](int bsel) {
#pragma unroll
        for (int ks = 0; ks < 2; ++ks) {
            const int kk = ks * 32 + (lane >> 4) * 8;
            f16x8 a[4], b[4];
#pragma unroll
            for (int i = 0; i < 4; ++i) {
                const int ra = wr * 64 + i * 16 + (lane & 15);
                a[i] = *(const f16x8*)(&sA[bsel][(ra << 6) + (kk ^ ((ra & 7) << 3))]);
                const int rb2 = wc * 64 + i * 16 + (lane & 15);
                b[i] = *(const f16x8*)(&sB[bsel][(rb2 << 6) + (kk ^ ((rb2 & 7) << 3))]);
            }
#pragma unroll
            for (int i = 0; i < 4; ++i)
#pragma unroll
                for (int j = 0; j < 4; ++j)
                    acc[i][j] = __builtin_amdgcn_mfma_f32_16x16x32_f16(a[i], b[j], acc[i][j], 0, 0, 0);
        }
    };

    if constexpr (PIPE) {
        stage16(0, 0);
        asm volatile("s_waitcnt vmcnt(0)" ::: "memory");
        __syncthreads();
        const int NT2 = K >> 6;
        for (int t = 0; t < NT2; ++t) {
            if (t + 1 < NT2) stage16((t + 1) << 6, (t + 1) & 1);
            compute(t & 1);
            asm volatile("s_waitcnt vmcnt(0)" ::: "memory");
            __builtin_amdgcn_s_barrier();
        }
    } else {
        for (int kt = 0; kt < K; kt += 64) {
            __syncthreads();
            stage16(kt, 0);
            __syncthreads();
            compute(0);
        }
    }
#pragma unroll
    for (int i = 0; i < 4; ++i)
#pragma unroll
        for (int j = 0; j < 4; ++j)
#pragma unroll
            for (int r = 0; r < 4; ++r) {
                const int row = bm + wr * 64 + i * 16 + (lane >> 4) * 4 + r;
                const int col = bn + wc * 64 + j * 16 + (lane & 15);
                if constexpr (F16OUT)
                    ((f16*)Cv)[(size_t)row * ldc + col] = (f16)acc[i][j][r];
                else
                    ((float*)Cv)[(size_t)row * ldc + col] = acc[i][j][r] * scale;
            }
}

// ---------------------------------------------------------------------------
__global__ __launch_bounds__(256) void cvt_f16(
    const float* __restrict__ s, f16* __restrict__ d, int n8)
{
    int i = blockIdx.x * 256 + threadIdx.x;
    const int stride = gridDim.x * 256;
    for (; i < n8; i += stride) {
        const float4 a = ((const float4*)s)[i * 2];
        const float4 b = ((const float4*)s)[i * 2 + 1];
        f16x8 o = { (f16)a.x, (f16)a.y, (f16)a.z, (f16)a.w,
                    (f16)b.x, (f16)b.y, (f16)b.z, (f16)b.w };
        ((f16x8*)d)[i] = o;
    }
}

__global__ __launch_bounds__(256) void zerof(float* __restrict__ p, int n4)
{
    int i = blockIdx.x * 256 + threadIdx.x;
    const int stride = gridDim.x * 256;
    const float4 z = {0.f, 0.f, 0.f, 0.f};
    for (; i < n4; i += stride) ((float4*)p)[i] = z;
}

// ---------------------------------------------------------------------------
// In-place row softmax (verified): 4096-f32 row -> f16 into first 8KB of row.
// ---------------------------------------------------------------------------
__global__ __launch_bounds__(256) void softmax_inplace(float* S)
{
    const int lane = threadIdx.x & 63, wid = threadIdx.x >> 6;
    const int row = blockIdx.x * 4 + wid;
    float* src = S + (size_t)row * 4096;
    float4 v[16];
#pragma unroll
    for (int u = 0; u < 16; ++u)
        v[u] = ((const float4*)src)[u * 64 + lane];
    float m = -1e30f;
#pragma unroll
    for (int u = 0; u < 16; ++u)
        m = fmaxf(m, fmaxf(fmaxf(v[u].x, v[u].y), fmaxf(v[u].z, v[u].w)));
#pragma unroll
    for (int msk = 1; msk <= 32; msk <<= 1) m = fmaxf(m, __shfl_xor(m, msk));
    float s = 0.f;
#pragma unroll
    for (int u = 0; u < 16; ++u) {
        v[u].x = __expf(v[u].x - m); v[u].y = __expf(v[u].y - m);
        v[u].z = __expf(v[u].z - m); v[u].w = __expf(v[u].w - m);
        s += (v[u].x + v[u].y) + (v[u].z + v[u].w);
    }
#pragma unroll
    for (int msk = 1; msk <= 32; msk <<= 1) s += __shfl_xor(s, msk);
    const float inv = 1.0f / s;
    f16* dst = (f16*)S + (size_t)row * 8192;
#pragma unroll
    for (int u = 0; u < 16; ++u) {
        f16x4 p = { (f16)(v[u].x * inv), (f16)(v[u].y * inv),
                    (f16)(v[u].z * inv), (f16)(v[u].w * inv) };
        *(f16x4*)(dst + u * 256 + lane * 4) = p;
    }
}

// ---------------------------------------------------------------------------
// Pipeline: cvt -> proj(bt8) -> per batch { QK(bt8) -> SM -> cvt x_b,Wv ->
// vT(PIPE) -> zero out_b -> PV(bt8 split-K=4 atomic) }.
// ---------------------------------------------------------------------------
extern "C" void kernel_launch(void* const* d_in, const int* in_sizes, int n_in,
                              void* d_out, int out_size, void* d_ws, size_t ws_size,
                              hipStream_t stream) {
    const float* x  = (const float*)d_in[0];   // [4,4096,1024]
    const float* Wq = (const float*)d_in[1];   // [1024,1024]
    const float* Wk = (const float*)d_in[2];
    const float* Wv = (const float*)d_in[3];
    float* out = (float*)d_out;                // [4,4096,1024] fp32

    f16*   qk  = (f16*)d_out;                  // q even 1KB-slots, k odd
    f16*   xh  = (f16*)d_ws;                   // 32 MB (transient)
    f16*   wqh = xh + 16384LL * 1024;          // 2 MB
    f16*   wkh = wqh + 1024LL * 1024;          // 2 MB
    float* Sf  = (float*)d_ws;                 // 64 MB S region
    f16*   Sh  = (f16*)d_ws;
    f16*   vTp = Sh + 3072LL * 8192 + 4096;    // vT in second halves of rows 3072+

    cvt_f16<<<1024, 256, 0, stream>>>(x,  xh,  16384 * 1024 / 8);
    cvt_f16<<<512,  256, 0, stream>>>(Wq, wqh, 1024 * 1024 / 8);
    cvt_f16<<<512,  256, 0, stream>>>(Wk, wkh, 1024 * 1024 / 8);

    gemm_bt8<true><<<256, 512, 0, stream>>>(xh, wqh, qk,        1024, 1024, 1024, 2048, 1.f, 4);
    gemm_bt8<true><<<256, 512, 0, stream>>>(xh, wkh, qk + 1024, 1024, 1024, 1024, 2048, 1.f, 4);

    for (int b = 0; b < 4; ++b) {
        const size_t tb = (size_t)b * 4096;
        f16* xhb = (f16*)(out + tb * 1024);        // dead q_b/k_b region (16 MB)
        f16* wvh = xhb + 4096LL * 1024;            // +8 MB
        // S = q_b k_b^T
        gemm_bt8<false><<<256, 512, 0, stream>>>(
            qk + tb * 2048, qk + tb * 2048 + 1024, Sf,
            1024, 2048, 2048, 4096, 1.f, 16);
        // softmax in place -> P (first halves, lda 8192)
        softmax_inplace<<<1024, 256, 0, stream>>>(Sf);
        // re-cvt x_b, Wv into dead out_b region
        cvt_f16<<<1024, 256, 0, stream>>>(x + tb * 1024, xhb, 4096 * 1024 / 8);
        cvt_f16<<<512,  256, 0, stream>>>(Wv, wvh, 1024 * 1024 / 8);
        // vT_b = Wv_h x_b^T  (F16IN PIPE) -> second halves of rows 3072..4095
        gemm_bt<true, true, true><<<dim3(8, 32), 256, 0, stream>>>(
            wvh, xhb, vTp, 1024, 1024, 1024, 8192, 1.f);
        // zero out_b, then att_b = (P vT^T)/32, bt8 core + split-K=4 atomics
        zerof<<<2048, 256, 0, stream>>>(out + tb * 1024, 4096 * 1024 / 4);
        gemm_pv8<<<dim3(64, 4), 512, 0, stream>>>(
            Sh, vTp, out + tb * 1024, 8192, 8192, 1024, 1.f / 32.f);
    }
}

// Round 12
// 616.267 us; speedup vs baseline: 1.2469x; 1.2469x over previous
//
#include <hip/hip_runtime.h>
#include <hip/hip_bf16.h>

typedef _Float16 f16;
typedef _Float16 f16x4 __attribute__((ext_vector_type(4)));
typedef _Float16 f16x8 __attribute__((ext_vector_type(8)));
typedef float f32x4 __attribute__((ext_vector_type(4)));

__device__ __forceinline__ void gload16(const void* g, void* l) {
    __builtin_amdgcn_global_load_lds(
        (const __attribute__((address_space(1))) void*)g,
        (__attribute__((address_space(3))) void*)l, 16, 0, 0);
}

#define FENCE asm volatile("" ::: "memory")
#define BARRIER do { FENCE; __builtin_amdgcn_s_barrier(); FENCE; } while (0)

// ===========================================================================
// 8-phase 256x256 BT-GEMM core (verified r8): per K-tile 4 phases, one
// C-quadrant each; stage next tile A at ph1, B at ph2; single vmcnt(0) at ph4.
// ===========================================================================
#define PHASE_MFMA(QI, QJ)                                                    \
    __builtin_amdgcn_s_setprio(1);                                            \
    _Pragma("unroll")                                                         \
    for (int ks = 0; ks < 2; ++ks)                                            \
      _Pragma("unroll")                                                       \
      for (int i = 0; i < 4; ++i)                                             \
        _Pragma("unroll")                                                     \
        for (int j = 0; j < 2; ++j)                                           \
          acc[(QI)*4 + i][(QJ)*2 + j] = __builtin_amdgcn_mfma_f32_16x16x32_f16( \
              a[i][ks], b[j][ks], acc[(QI)*4 + i][(QJ)*2 + j], 0, 0, 0);      \
    __builtin_amdgcn_s_setprio(0);

#define BT8_BODY(KBASE, NTILES)                                               \
    const int rr8 = lane >> 3;                                                \
    const int cs  = ((lane & 7) ^ rr8) << 3;                                  \
    const int ldsr = wid << 3;                                                \
    auto stageA = [&](int kt, int c, int h) {                                 \
        const size_t g0 = (size_t)(bm + (h << 7) + ldsr + rr8) * lda + (KBASE) + kt + cs; \
        gload16(A + g0,                      &sA[c][((h << 7) + ldsr) << 6]); \
        gload16(A + g0 + ((size_t)lda << 6), &sA[c][((h << 7) + 64 + ldsr) << 6]); \
    };                                                                        \
    auto stageB = [&](int kt, int c, int h) {                                 \
        const size_t g0 = (size_t)(bn + (h << 7) + ldsr + rr8) * ldb + (KBASE) + kt + cs; \
        gload16(B + g0,                      &sB[c][((h << 7) + ldsr) << 6]); \
        gload16(B + g0 + ((size_t)ldb << 6), &sB[c][((h << 7) + 64 + ldsr) << 6]); \
    };                                                                        \
    f32x4 acc[8][4] = {};                                                     \
    f16x8 a[4][2], b[2][2];                                                   \
    auto loadA = [&](int c, int qi) {                                         \
        _Pragma("unroll")                                                     \
        for (int i = 0; i < 4; ++i) {                                         \
            const int ra = wr * 128 + (qi * 4 + i) * 16 + (lane & 15);        \
            const int swz = (ra & 7) << 3;                                    \
            _Pragma("unroll")                                                 \
            for (int ks = 0; ks < 2; ++ks) {                                  \
                const int kk = ks * 32 + (lane >> 4) * 8;                     \
                a[i][ks] = *(const f16x8*)(&sA[c][(ra << 6) + (kk ^ swz)]);   \
            }                                                                 \
        }                                                                     \
    };                                                                        \
    auto loadB = [&](int c, int qj) {                                         \
        _Pragma("unroll")                                                     \
        for (int j = 0; j < 2; ++j) {                                         \
            const int rb = wc * 64 + (qj * 2 + j) * 16 + (lane & 15);         \
            const int swz = (rb & 7) << 3;                                    \
            _Pragma("unroll")                                                 \
            for (int ks = 0; ks < 2; ++ks) {                                  \
                const int kk = ks * 32 + (lane >> 4) * 8;                     \
                b[j][ks] = *(const f16x8*)(&sB[c][(rb << 6) + (kk ^ swz)]);   \
            }                                                                 \
        }                                                                     \
    };                                                                        \
    stageA(0, 0, 0); stageA(0, 0, 1); stageB(0, 0, 0); stageB(0, 0, 1);       \
    asm volatile("s_waitcnt vmcnt(0)" ::: "memory");                          \
    BARRIER;                                                                  \
    for (int g = 0; g < (NTILES); ++g) {                                      \
        const int c = g & 1, cn = c ^ 1;                                      \
        const int kn = (g + 1) << 6;                                          \
        const bool more = (g + 1) < (NTILES);                                 \
        loadA(c, 0); loadB(c, 0);                                             \
        if (more) { stageA(kn, cn, 0); stageA(kn, cn, 1); }                   \
        BARRIER; PHASE_MFMA(0, 0); BARRIER;                                   \
        loadB(c, 1);                                                          \
        if (more) { stageB(kn, cn, 0); stageB(kn, cn, 1); }                   \
        BARRIER; PHASE_MFMA(0, 1); BARRIER;                                   \
        loadA(c, 1); loadB(c, 0);                                             \
        BARRIER; PHASE_MFMA(1, 0); BARRIER;                                   \
        loadB(c, 1);                                                          \
        asm volatile("s_waitcnt vmcnt(0)" ::: "memory");                      \
        BARRIER; PHASE_MFMA(1, 1); BARRIER;                                   \
    }

template<bool F16OUT>
__global__ __launch_bounds__(512) void gemm_bt8(
    const f16* __restrict__ A, const f16* __restrict__ B, void* __restrict__ Cv,
    int K, int lda, int ldb, int ldc, float scale, int nbn)
{
    __shared__ f16 sA[2][256 * 64];
    __shared__ f16 sB[2][256 * 64];
    const int tid = threadIdx.x, lane = tid & 63, wid = tid >> 6;
    const int wr = wid >> 2, wc = wid & 3;
    const int cpx = gridDim.x >> 3;
    const int wg = (blockIdx.x & 7) * cpx + (blockIdx.x >> 3);
    const int bm = (wg / nbn) << 8, bn = (wg % nbn) << 8;

    BT8_BODY(0, K >> 6)

#pragma unroll
    for (int i = 0; i < 8; ++i)
#pragma unroll
        for (int j = 0; j < 4; ++j)
#pragma unroll
            for (int r = 0; r < 4; ++r) {
                const int row = bm + wr * 128 + i * 16 + ((lane >> 4) << 2) + r;
                const int col = bn + wc * 64 + j * 16 + (lane & 15);
                if constexpr (F16OUT)
                    ((f16*)Cv)[(size_t)row * ldc + col] = (f16)(acc[i][j][r] * scale);
                else
                    ((float*)Cv)[(size_t)row * ldc + col] = acc[i][j][r] * scale;
            }
}

// ===========================================================================
// PV: bt8 core + split-K=4, NO atomics. Chunk z=3 stores f32 directly to
// out_b[r][c]; chunks z=0..2 store scaled f16 partials into the free second
// halves of S rows 0..3071: p_z[r][c] = Sh[(1024z + (r>>2))*8192 + 4096 +
// (r&3)*1024 + c]. reduce_pv sums them deterministically.
// Grid (64, 4) = 256 blocks = 1/CU.
// ===========================================================================
__global__ __launch_bounds__(512) void gemm_pv8(
    const f16* __restrict__ A, const f16* __restrict__ B, float* __restrict__ Cout,
    f16* __restrict__ Pp, int lda, int ldb, float scale)
{
    __shared__ f16 sA[2][256 * 64];
    __shared__ f16 sB[2][256 * 64];
    const int tid = threadIdx.x, lane = tid & 63, wid = tid >> 6;
    const int wr = wid >> 2, wc = wid & 3;
    const int cpx = gridDim.x >> 3;
    const int wg = (blockIdx.x & 7) * cpx + (blockIdx.x >> 3);
    const int bm = (wg >> 2) << 8, bn = (wg & 3) << 8;
    const int z = blockIdx.y;
    const int kbase = z << 10;

    BT8_BODY(kbase, 16)

#pragma unroll
    for (int i = 0; i < 8; ++i)
#pragma unroll
        for (int j = 0; j < 4; ++j)
#pragma unroll
            for (int r = 0; r < 4; ++r) {
                const int row = bm + wr * 128 + i * 16 + ((lane >> 4) << 2) + r;
                const int col = bn + wc * 64 + j * 16 + (lane & 15);
                const float v = acc[i][j][r] * scale;
                if (z == 3) {
                    Cout[(size_t)row << 10 | col] = v;
                } else {
                    const size_t off = ((size_t)((z << 10) + (row >> 2)) << 13)
                                       + 4096 + ((row & 3) << 10) + col;
                    Pp[off] = (f16)v;
                }
            }
}

// ===========================================================================
// reduce_pv: out[r][c] = out[r][c](=p3) + p0 + p1 + p2. Same-address
// read-then-write per element -> deterministic, race-free.
// 8 elements/thread; grid 2048x256 covers 4096x1024.
// ===========================================================================
__global__ __launch_bounds__(256) void reduce_pv(
    float* __restrict__ Cout, const f16* __restrict__ Pp)
{
    const int i = blockIdx.x * 256 + threadIdx.x;   // 524288 threads
    const int r = i >> 7;            // row (8 elems/thread: 128 threads/row)
    const int c = (i & 127) << 3;    // col base
    const size_t base = ((size_t)(r >> 2) << 13) + 4096 + ((r & 3) << 10) + c;
    const f16x8 p0 = *(const f16x8*)(Pp + base);
    const f16x8 p1 = *(const f16x8*)(Pp + base + (1024LL << 13));
    const f16x8 p2 = *(const f16x8*)(Pp + base + (2048LL << 13));
    float* o = Cout + ((size_t)r << 10) + c;
    float4 o0 = *(float4*)o, o1 = *(float4*)(o + 4);
    o0.x += (float)p0[0] + (float)p1[0] + (float)p2[0];
    o0.y += (float)p0[1] + (float)p1[1] + (float)p2[1];
    o0.z += (float)p0[2] + (float)p1[2] + (float)p2[2];
    o0.w += (float)p0[3] + (float)p1[3] + (float)p2[3];
    o1.x += (float)p0[4] + (float)p1[4] + (float)p2[4];
    o1.y += (float)p0[5] + (float)p1[5] + (float)p2[5];
    o1.z += (float)p0[6] + (float)p1[6] + (float)p2[6];
    o1.w += (float)p0[7] + (float)p1[7] + (float)p2[7];
    *(float4*)o = o0;
    *(float4*)(o + 4) = o1;
}

// ===========================================================================
// 128x128 BT-GEMM, F16IN + PIPE (verified) — used for vT.
// ===========================================================================
template<bool F16IN, bool F16OUT, bool PIPE>
__global__ __launch_bounds__(256) void gemm_bt(
    const void* __restrict__ Av, const void* __restrict__ Bv, void* __restrict__ Cv,
    int K, int lda, int ldb, int ldc, float scale)
{
    constexpr int NB = PIPE ? 2 : 1;
    __shared__ f16 sA[NB][128 * 64];
    __shared__ f16 sB[NB][128 * 64];
    const int tid = threadIdx.x, lane = tid & 63, wid = tid >> 6;
    const int wr = wid >> 1, wc = wid & 1;
    const int bm = blockIdx.x * 128, bn = blockIdx.y * 128;

    f32x4 acc[4][4] = {};

    auto stage16 = [&](int kt, int bsel) {
        const f16* A = (const f16*)Av;
        const f16* B = (const f16*)Bv;
        const int rsub = lane >> 3;
        const int csw = ((lane & 7) ^ rsub) << 3;
#pragma unroll
        for (int i = 0; i < 4; ++i) {
            const int rb = (wid * 4 + i) * 8;
            gload16(A + (size_t)(bm + rb + rsub) * lda + kt + csw, &sA[bsel][rb * 64]);
            gload16(B + (size_t)(bn + rb + rsub) * ldb + kt + csw, &sB[bsel][rb * 64]);
        }
    };

    auto compute = [&](int bsel) {
#pragma unroll
        for (int ks = 0; ks < 2; ++ks) {
            const int kk = ks * 32 + (lane >> 4) * 8;
            f16x8 a[4], b[4];
#pragma unroll
            for (int i = 0; i < 4; ++i) {
                const int ra = wr * 64 + i * 16 + (lane & 15);
                a[i] = *(const f16x8*)(&sA[bsel][(ra << 6) + (kk ^ ((ra & 7) << 3))]);
                const int rb2 = wc * 64 + i * 16 + (lane & 15);
                b[i] = *(const f16x8*)(&sB[bsel][(rb2 << 6) + (kk ^ ((rb2 & 7) << 3))]);
            }
#pragma unroll
            for (int i = 0; i < 4; ++i)
#pragma unroll
                for (int j = 0; j < 4; ++j)
                    acc[i][j] = __builtin_amdgcn_mfma_f32_16x16x32_f16(a[i], b[j], acc[i][j], 0, 0, 0);
        }
    };

    if constexpr (PIPE) {
        stage16(0, 0);
        asm volatile("s_waitcnt vmcnt(0)" ::: "memory");
        __syncthreads();
        const int NT2 = K >> 6;
        for (int t = 0; t < NT2; ++t) {
            if (t + 1 < NT2) stage16((t + 1) << 6, (t + 1) & 1);
            compute(t & 1);
            asm volatile("s_waitcnt vmcnt(0)" ::: "memory");
            __builtin_amdgcn_s_barrier();
        }
    } else {
        for (int kt = 0; kt < K; kt += 64) {
            __syncthreads();
            stage16(kt, 0);
            __syncthreads();
            compute(0);
        }
    }
#pragma unroll
    for (int i = 0; i < 4; ++i)
#pragma unroll
        for (int j = 0; j < 4; ++j)
#pragma unroll
            for (int r = 0; r < 4; ++r) {
                const int row = bm + wr * 64 + i * 16 + (lane >> 4) * 4 + r;
                const int col = bn + wc * 64 + j * 16 + (lane & 15);
                if constexpr (F16OUT)
                    ((f16*)Cv)[(size_t)row * ldc + col] = (f16)acc[i][j][r];
                else
                    ((float*)Cv)[(size_t)row * ldc + col] = acc[i][j][r] * scale;
            }
}

// ---------------------------------------------------------------------------
__global__ __launch_bounds__(256) void cvt_f16(
    const float* __restrict__ s, f16* __restrict__ d, int n8)
{
    int i = blockIdx.x * 256 + threadIdx.x;
    const int stride = gridDim.x * 256;
    for (; i < n8; i += stride) {
        const float4 a = ((const float4*)s)[i * 2];
        const float4 b = ((const float4*)s)[i * 2 + 1];
        f16x8 o = { (f16)a.x, (f16)a.y, (f16)a.z, (f16)a.w,
                    (f16)b.x, (f16)b.y, (f16)b.z, (f16)b.w };
        ((f16x8*)d)[i] = o;
    }
}

// ---------------------------------------------------------------------------
// In-place row softmax (verified): 4096-f32 row -> f16 into first 8KB of row.
// ---------------------------------------------------------------------------
__global__ __launch_bounds__(256) void softmax_inplace(float* S)
{
    const int lane = threadIdx.x & 63, wid = threadIdx.x >> 6;
    const int row = blockIdx.x * 4 + wid;
    float* src = S + (size_t)row * 4096;
    float4 v[16];
#pragma unroll
    for (int u = 0; u < 16; ++u)
        v[u] = ((const float4*)src)[u * 64 + lane];
    float m = -1e30f;
#pragma unroll
    for (int u = 0; u < 16; ++u)
        m = fmaxf(m, fmaxf(fmaxf(v[u].x, v[u].y), fmaxf(v[u].z, v[u].w)));
#pragma unroll
    for (int msk = 1; msk <= 32; msk <<= 1) m = fmaxf(m, __shfl_xor(m, msk));
    float s = 0.f;
#pragma unroll
    for (int u = 0; u < 16; ++u) {
        v[u].x = __expf(v[u].x - m); v[u].y = __expf(v[u].y - m);
        v[u].z = __expf(v[u].z - m); v[u].w = __expf(v[u].w - m);
        s += (v[u].x + v[u].y) + (v[u].z + v[u].w);
    }
#pragma unroll
    for (int msk = 1; msk <= 32; msk <<= 1) s += __shfl_xor(s, msk);
    const float inv = 1.0f / s;
    f16* dst = (f16*)S + (size_t)row * 8192;
#pragma unroll
    for (int u = 0; u < 16; ++u) {
        f16x4 p = { (f16)(v[u].x * inv), (f16)(v[u].y * inv),
                    (f16)(v[u].z * inv), (f16)(v[u].w * inv) };
        *(f16x4*)(dst + u * 256 + lane * 4) = p;
    }
}

// ---------------------------------------------------------------------------
// Pipeline: cvt -> proj(bt8) -> per batch { QK(bt8) -> SM -> cvt x_b,Wv ->
// vT(PIPE) -> PV(bt8 split-K=4, plain stores) -> reduce }.
// ---------------------------------------------------------------------------
extern "C" void kernel_launch(void* const* d_in, const int* in_sizes, int n_in,
                              void* d_out, int out_size, void* d_ws, size_t ws_size,
                              hipStream_t stream) {
    const float* x  = (const float*)d_in[0];   // [4,4096,1024]
    const float* Wq = (const float*)d_in[1];   // [1024,1024]
    const float* Wk = (const float*)d_in[2];
    const float* Wv = (const float*)d_in[3];
    float* out = (float*)d_out;                // [4,4096,1024] fp32

    f16*   qk  = (f16*)d_out;                  // q even 1KB-slots, k odd
    f16*   xh  = (f16*)d_ws;                   // 32 MB (transient)
    f16*   wqh = xh + 16384LL * 1024;          // 2 MB
    f16*   wkh = wqh + 1024LL * 1024;          // 2 MB
    float* Sf  = (float*)d_ws;                 // 64 MB S region
    f16*   Sh  = (f16*)d_ws;
    f16*   vTp = Sh + 3072LL * 8192 + 4096;    // vT in second halves of rows 3072+

    cvt_f16<<<1024, 256, 0, stream>>>(x,  xh,  16384 * 1024 / 8);
    cvt_f16<<<512,  256, 0, stream>>>(Wq, wqh, 1024 * 1024 / 8);
    cvt_f16<<<512,  256, 0, stream>>>(Wk, wkh, 1024 * 1024 / 8);

    gemm_bt8<true><<<256, 512, 0, stream>>>(xh, wqh, qk,        1024, 1024, 1024, 2048, 1.f, 4);
    gemm_bt8<true><<<256, 512, 0, stream>>>(xh, wkh, qk + 1024, 1024, 1024, 1024, 2048, 1.f, 4);

    for (int b = 0; b < 4; ++b) {
        const size_t tb = (size_t)b * 4096;
        f16* xhb = (f16*)(out + tb * 1024);        // dead q_b/k_b region (16 MB)
        f16* wvh = xhb + 4096LL * 1024;            // +8 MB
        // S = q_b k_b^T
        gemm_bt8<false><<<256, 512, 0, stream>>>(
            qk + tb * 2048, qk + tb * 2048 + 1024, Sf,
            1024, 2048, 2048, 4096, 1.f, 16);
        // softmax in place -> P (first halves, lda 8192)
        softmax_inplace<<<1024, 256, 0, stream>>>(Sf);
        // re-cvt x_b, Wv into dead out_b region
        cvt_f16<<<1024, 256, 0, stream>>>(x + tb * 1024, xhb, 4096 * 1024 / 8);
        cvt_f16<<<512,  256, 0, stream>>>(Wv, wvh, 1024 * 1024 / 8);
        // vT_b = Wv_h x_b^T  (F16IN PIPE) -> second halves of rows 3072..4095
        gemm_bt<true, true, true><<<dim3(8, 32), 256, 0, stream>>>(
            wvh, xhb, vTp, 1024, 1024, 1024, 8192, 1.f);
        // att_b = (P vT^T)/32: bt8 core split-K=4, plain stores, then reduce
        gemm_pv8<<<dim3(64, 4), 512, 0, stream>>>(
            Sh, vTp, out + tb * 1024, Sh, 8192, 8192, 1.f / 32.f);
        reduce_pv<<<2048, 256, 0, stream>>>(out + tb * 1024, Sh);
    }
}